// Round 2
// baseline (243.351 us; speedup 1.0000x reference)
//
#include <hip/hip_runtime.h>
#include <cstdint>
#include <cstddef>

#define B_   128
#define NF_  64
#define L_   4096
#define K_   64
#define NG_  400

#define WIN_   192              // truncated Gaussian window (±96, tail < 2e-8)
#define NR_    (WIN_ / 4)       // 48 float4-groups per window
#define ROWP_  (128 + L_ + 128) // padded LDS row (4352 floats)

constexpr float STEP = 4096.0f / 4095.0f;                 // linspace(0,4096,4096) step
constexpr float NEGC = -1.4426950408889634f / 512.0f;     // -log2(e)/(2*sigma^2), sigma=16

// ---------------------------------------------------------------------------
// Weight bank precompute: Wrel[g][r][f][j] = amps[f,g]/4096 * exp(-(x-mu)^2/512)
// at sample index l = l0(f,g) + r*4 + j, x = l*STEP.  Also emits l0tab[g][f].
// 400*48*64*4 floats = 19.7 MB (L2/L3 resident).  ~5e6 exps, runs in a few us.
// ---------------------------------------------------------------------------
__global__ __launch_bounds__(256) void wbank_kernel(
    const float* __restrict__ mus, const float* __restrict__ amps,
    float* __restrict__ Wrel, int* __restrict__ l0tab)
{
    const int g = blockIdx.x;
    const int t = threadIdx.x;
    const int f = t >> 2;
    const int j = t & 3;

    const float mu = mus[f * NG_ + g];
    const float sc = amps[f * NG_ + g] * (1.0f / 4096.0f);
    const int   l0 = (((int)mu) - 96) & ~3;
    if (j == 0) l0tab[g * NF_ + f] = l0;

    float* __restrict__ Wg = Wrel + (size_t)g * (NR_ * NF_ * 4);
#pragma unroll 8
    for (int r = 0; r < NR_; ++r) {
        float d = fmaf((float)(l0 + r * 4 + j), STEP, -mu);
        Wg[r * 256 + f * 4 + j] = sc * exp2f(NEGC * d * d);
    }
}

// ---------------------------------------------------------------------------
// Hot kernel: filtered[b,f] += sum_l X[b,g,l] * Wrel[...]  for 2 batch rows.
// Block (g, b-pair): stage 2 X rows in LDS (zero-padded), 8 waves.
// Wave w: bb = w>>2 (which row), fhi = w&3; lane: flo = lane&15, i = lane>>4,
// f = fhi*16+flo.  Each (f,bb) group of 4 lanes sweeps its 192-sample window:
// per iter 1 ds_read_b128 (X) + 1 global_load_dwordx4 (W, L2) + 4 fma.
// ---------------------------------------------------------------------------
__global__ __launch_bounds__(512, 8) void filt_kernel(
    const float* __restrict__ X, const int* __restrict__ l0tab,
    const float* __restrict__ Wrel, float* __restrict__ filtered)
{
    const int g  = blockIdx.x;
    const int b0 = blockIdx.y * 2;
    const int t  = threadIdx.x;

    __shared__ __align__(16) float Xs[2][ROWP_];
    __shared__ int l0_s[NF_];

    // zero pads + l0 gather
    if (t < 128)      { Xs[0][t] = 0.0f;          Xs[1][t] = 0.0f; }
    else if (t < 256) { Xs[0][4096 + t] = 0.0f;   Xs[1][4096 + t] = 0.0f; }
    if (t < NF_) l0_s[t] = l0tab[g * NF_ + t];

    // coalesced float4 staging: waves 0-3 -> row 0, waves 4-7 -> row 1
    {
        const int rr = t >> 8;          // 0/1
        const int q  = t & 255;
        const float4* __restrict__ src =
            (const float4*)(X + ((size_t)(b0 + rr) * NG_ + g) * L_);
        float4* dst = (float4*)(Xs[rr] + 128);
#pragma unroll
        for (int r = 0; r < 4; ++r) dst[q + 256 * r] = src[q + 256 * r];
    }
    __syncthreads();

    const int lane = t & 63;
    const int w    = t >> 6;
    const int bb   = w >> 2;
    const int fhi  = w & 3;
    const int flo  = lane & 15;
    const int i    = lane >> 4;         // 4-lane group member (strided by 16)
    const int f    = fhi * 16 + flo;

    const float*  xp = Xs[bb] + 128 + l0_s[f] + i * 4;
    const float4* wp = (const float4*)(Wrel + (size_t)g * (NR_ * NF_ * 4))
                       + (i * NF_ + f);

    float acc = 0.0f;
#pragma unroll 4
    for (int itr = 0; itr < 12; ++itr) {
        float4 xv = *(const float4*)(xp + itr * 16);
        float4 wv = wp[itr * 256];      // advance 4 r-slabs (4 KB) per iter
        acc = fmaf(xv.x, wv.x, acc);
        acc = fmaf(xv.y, wv.y, acc);
        acc = fmaf(xv.z, wv.z, acc);
        acc = fmaf(xv.w, wv.w, acc);
    }
    // reduce the 4-lane group (members at lane, lane^16, lane^32, lane^48)
    acc += __shfl_xor(acc, 16);
    acc += __shfl_xor(acc, 32);
    if (i == 0) atomicAdd(&filtered[(b0 + bb) * NF_ + f], acc);
}

// ---------------------------------------------------------------------------
// MLP head (tiny): elu/reparam + 3 small GEMVs with exact gelu.
// out layout: coms[128*400] | pred[128*400] | mu[128*64] | log_sig[128*64]
// ---------------------------------------------------------------------------
__device__ __forceinline__ float gelu_exact(float x) {
    return 0.5f * x * (1.0f + erff(x * 0.70710678118654752f));
}

__global__ __launch_bounds__(256) void head_kernel(
    const float* __restrict__ filtered, const float* __restrict__ eps,
    const float* __restrict__ Wmu,  const float* __restrict__ bmu,
    const float* __restrict__ Wsig, const float* __restrict__ bsig,
    const float* __restrict__ W01,  const float* __restrict__ b01,
    const float* __restrict__ W1,   const float* __restrict__ b1,
    const float* __restrict__ W2,   const float* __restrict__ b2,
    float* __restrict__ out)
{
    const int b = blockIdx.x;
    const int t = threadIdx.x;
    __shared__ float fil[NF_], lat[K_], hh[K_];

    if (t < NF_) fil[t] = filtered[b * NF_ + t];
    __syncthreads();

    if (t < K_) {
        float am = bmu[t], as = bsig[t];
#pragma unroll 8
        for (int fj = 0; fj < NF_; ++fj) {
            float x = fil[fj];
            am = fmaf(x, Wmu [t * NF_ + fj], am);
            as = fmaf(x, Wsig[t * NF_ + fj], as);
        }
        float muv = am > 0.0f ? am : expm1f(am);
        float lsv = as > 0.0f ? as : expm1f(as);
        out[2 * B_ * NG_            + b * K_ + t] = muv;   // mu
        out[2 * B_ * NG_ + B_ * K_  + b * K_ + t] = lsv;   // log_sig
        lat[t] = fmaf(eps[b * K_ + t], expf(lsv), muv);
    }
    __syncthreads();

    if (t < K_) {
        float a = b01[t];
#pragma unroll 8
        for (int j = 0; j < K_; ++j) a = fmaf(lat[j], W01[t * K_ + j], a);
        hh[t] = gelu_exact(a);
    }
    __syncthreads();

    for (int n = t; n < NG_; n += 256) {
        float a1 = b1[n], a2 = b2[n];
#pragma unroll 8
        for (int k = 0; k < K_; ++k) {
            float hk = hh[k];
            a1 = fmaf(hk, W1[n * K_ + k], a1);
            a2 = fmaf(hk, W2[n * K_ + k], a2);
        }
        out[            b * NG_ + n] = gelu_exact(a1);   // coms
        out[B_ * NG_ +  b * NG_ + n] = gelu_exact(a2);   // pred_num_spikes
    }
}

extern "C" void kernel_launch(void* const* d_in, const int* in_sizes, int n_in,
                              void* d_out, int out_size, void* d_ws, size_t ws_size,
                              hipStream_t stream) {
    const float* X    = (const float*)d_in[0];
    const float* eps  = (const float*)d_in[1];
    const float* mus  = (const float*)d_in[2];
    const float* amps = (const float*)d_in[3];
    const float* Wmu  = (const float*)d_in[4];
    const float* bmu  = (const float*)d_in[5];
    const float* Wsig = (const float*)d_in[6];
    const float* bsig = (const float*)d_in[7];
    const float* W01  = (const float*)d_in[8];
    const float* b01  = (const float*)d_in[9];
    const float* W1   = (const float*)d_in[10];
    const float* b1   = (const float*)d_in[11];
    const float* W2   = (const float*)d_in[12];
    const float* b2   = (const float*)d_in[13];

    float* out = (float*)d_out;

    // workspace layout
    float* filtered = (float*)d_ws;                               // 8192 f32
    int*   l0tab    = (int*)((char*)d_ws + 32768);                // 25600 i32
    float* Wrel     = (float*)((char*)d_ws + 32768 + 102400);     // 4.9M f32

    hipMemsetAsync(filtered, 0, B_ * NF_ * sizeof(float), stream);

    wbank_kernel<<<NG_, 256, 0, stream>>>(mus, amps, Wrel, l0tab);
    filt_kernel<<<dim3(NG_, B_ / 2), 512, 0, stream>>>(X, l0tab, Wrel, filtered);
    head_kernel<<<B_, 256, 0, stream>>>(filtered, eps, Wmu, bmu, Wsig, bsig,
                                        W01, b01, W1, b1, W2, b2, out);
}

// Round 3
// 212.227 us; speedup vs baseline: 1.1467x; 1.1467x over previous
//
#include <hip/hip_runtime.h>
#include <cstdint>
#include <cstddef>

#define B_   128
#define NF_  64
#define L_   4096
#define K_   64
#define NG_  400

#define ROWS_ 4                   // batch rows per block (weight reuse factor)
#define ROWP_ (128 + L_ + 128)    // padded LDS row: 4352 floats (136*32 words)

constexpr float STEP = 4096.0f / 4095.0f;              // linspace(0,4096,4096) step
constexpr float NEGC = -1.4426950408889634f / 512.0f;  // -log2(e)/(2*sigma^2), sigma=16

// ---------------------------------------------------------------------------
// filtered[b,f] = (1/4096) * sum_{g,l} X[b,g,l]*amps[f,g]*exp(-(x_l-mu_fg)^2/512)
// Gaussian truncated to 192 samples around mu (tail < 2e-8).
// Block = (g, 4 batch rows). 512 threads = 64 filters x 8 lanes.
//  - stage 4 zero-padded X rows in LDS (coalesced float4)
//  - each thread computes its 24 window weights ONCE (registers), applies to
//    all 4 rows: per c-iter 4x ds_read_b128 + 16 fma
//  - 8-lane groups are CONSECUTIVE lanes reading 8 consecutive float4s
//    -> each group touches all 32 banks exactly once (conflict-free)
//  - shfl_xor reduce over the 8 lanes, one atomicAdd per (row, filter)
// ---------------------------------------------------------------------------
__global__ __launch_bounds__(512, 4) void filt_kernel(
    const float* __restrict__ X, const float* __restrict__ mus,
    const float* __restrict__ amps, float* __restrict__ filtered)
{
    const int g  = blockIdx.x;
    const int b0 = blockIdx.y * ROWS_;
    const int t  = threadIdx.x;

    __shared__ __align__(16) float Xs[ROWS_][ROWP_];

    // ---- issue the 4-row staging loads (8 coalesced float4 per thread) ----
    float4 xv[8];
#pragma unroll
    for (int r = 0; r < 8; ++r) {
        const int u  = r * 512 + t;      // float4 unit 0..4095
        const int rr = u >> 10;          // row 0..3
        const int q  = u & 1023;         // float4 within row
        xv[r] = ((const float4*)(X + ((size_t)(b0 + rr) * NG_ + g) * L_))[q];
    }

    // ---- zero the pads (128 floats each side per row) ----
    if (t < 256) {
        const int rr = t >> 6, rem = t & 63;
        float4* praw = (float4*)Xs[rr];
        if (rem < 32) praw[rem]               = float4{0.f, 0.f, 0.f, 0.f};
        else          praw[1056 + (rem - 32)] = float4{0.f, 0.f, 0.f, 0.f};
    }

    // ---- per-thread weights (computed once, reused for all 4 rows) ----
    // thread t: filter f = t>>3, window float4 slot i = t&7
    // covers window offsets s = 4i + 32c + j  (c=0..5, j=0..3) -> 0..191
    const int f = t >> 3, i = t & 7;
    const float mu = mus[f * NG_ + g];
    const float sc = amps[f * NG_ + g] * (1.0f / 4096.0f);
    const int   l0 = (((int)mu) - 96) & ~3;    // 16B-aligned window start

    float w[6][4];
#pragma unroll
    for (int c = 0; c < 6; ++c) {
#pragma unroll
        for (int j = 0; j < 4; ++j) {
            float d = fmaf((float)(l0 + 4 * i + 32 * c + j), STEP, -mu);
            w[c][j] = sc * exp2f(NEGC * d * d);
        }
    }

    // ---- write staged rows to LDS ----
#pragma unroll
    for (int r = 0; r < 8; ++r) {
        const int u  = r * 512 + t;
        const int rr = u >> 10;
        const int q  = u & 1023;
        *(float4*)(&Xs[rr][128 + q * 4]) = xv[r];
    }
    __syncthreads();

    // ---- windowed dot products, 4 rows ----
    float acc0 = 0.f, acc1 = 0.f, acc2 = 0.f, acc3 = 0.f;
    const int base = 128 + l0 + 4 * i;
#pragma unroll
    for (int c = 0; c < 6; ++c) {
        const int o = base + 32 * c;
        float4 x0 = *(const float4*)(&Xs[0][o]);
        float4 x1 = *(const float4*)(&Xs[1][o]);
        float4 x2 = *(const float4*)(&Xs[2][o]);
        float4 x3 = *(const float4*)(&Xs[3][o]);
        acc0 = fmaf(x0.x, w[c][0], fmaf(x0.y, w[c][1], fmaf(x0.z, w[c][2], fmaf(x0.w, w[c][3], acc0))));
        acc1 = fmaf(x1.x, w[c][0], fmaf(x1.y, w[c][1], fmaf(x1.z, w[c][2], fmaf(x1.w, w[c][3], acc1))));
        acc2 = fmaf(x2.x, w[c][0], fmaf(x2.y, w[c][1], fmaf(x2.z, w[c][2], fmaf(x2.w, w[c][3], acc2))));
        acc3 = fmaf(x3.x, w[c][0], fmaf(x3.y, w[c][1], fmaf(x3.z, w[c][2], fmaf(x3.w, w[c][3], acc3))));
    }

    // ---- reduce across the 8 lanes sharing this filter ----
#pragma unroll
    for (int d = 1; d < 8; d <<= 1) {
        acc0 += __shfl_xor(acc0, d);
        acc1 += __shfl_xor(acc1, d);
        acc2 += __shfl_xor(acc2, d);
        acc3 += __shfl_xor(acc3, d);
    }
    if (i == 0) {
        atomicAdd(&filtered[(b0 + 0) * NF_ + f], acc0);
        atomicAdd(&filtered[(b0 + 1) * NF_ + f], acc1);
        atomicAdd(&filtered[(b0 + 2) * NF_ + f], acc2);
        atomicAdd(&filtered[(b0 + 3) * NF_ + f], acc3);
    }
}

// ---------------------------------------------------------------------------
// MLP head (tiny): elu/reparam + 3 small GEMVs with exact gelu.
// out layout: coms[128*400] | pred[128*400] | mu[128*64] | log_sig[128*64]
// ---------------------------------------------------------------------------
__device__ __forceinline__ float gelu_exact(float x) {
    return 0.5f * x * (1.0f + erff(x * 0.70710678118654752f));
}

__global__ __launch_bounds__(256) void head_kernel(
    const float* __restrict__ filtered, const float* __restrict__ eps,
    const float* __restrict__ Wmu,  const float* __restrict__ bmu,
    const float* __restrict__ Wsig, const float* __restrict__ bsig,
    const float* __restrict__ W01,  const float* __restrict__ b01,
    const float* __restrict__ W1,   const float* __restrict__ b1,
    const float* __restrict__ W2,   const float* __restrict__ b2,
    float* __restrict__ out)
{
    const int b = blockIdx.x;
    const int t = threadIdx.x;
    __shared__ float fil[NF_], lat[K_], hh[K_];

    if (t < NF_) fil[t] = filtered[b * NF_ + t];
    __syncthreads();

    if (t < K_) {
        float am = bmu[t], as = bsig[t];
#pragma unroll 8
        for (int fj = 0; fj < NF_; ++fj) {
            float x = fil[fj];
            am = fmaf(x, Wmu [t * NF_ + fj], am);
            as = fmaf(x, Wsig[t * NF_ + fj], as);
        }
        float muv = am > 0.0f ? am : expm1f(am);
        float lsv = as > 0.0f ? as : expm1f(as);
        out[2 * B_ * NG_            + b * K_ + t] = muv;   // mu
        out[2 * B_ * NG_ + B_ * K_  + b * K_ + t] = lsv;   // log_sig
        lat[t] = fmaf(eps[b * K_ + t], expf(lsv), muv);
    }
    __syncthreads();

    if (t < K_) {
        float a = b01[t];
#pragma unroll 8
        for (int j = 0; j < K_; ++j) a = fmaf(lat[j], W01[t * K_ + j], a);
        hh[t] = gelu_exact(a);
    }
    __syncthreads();

    for (int n = t; n < NG_; n += 256) {
        float a1 = b1[n], a2 = b2[n];
#pragma unroll 8
        for (int k = 0; k < K_; ++k) {
            float hk = hh[k];
            a1 = fmaf(hk, W1[n * K_ + k], a1);
            a2 = fmaf(hk, W2[n * K_ + k], a2);
        }
        out[            b * NG_ + n] = gelu_exact(a1);   // coms
        out[B_ * NG_ +  b * NG_ + n] = gelu_exact(a2);   // pred_num_spikes
    }
}

extern "C" void kernel_launch(void* const* d_in, const int* in_sizes, int n_in,
                              void* d_out, int out_size, void* d_ws, size_t ws_size,
                              hipStream_t stream) {
    const float* X    = (const float*)d_in[0];
    const float* eps  = (const float*)d_in[1];
    const float* mus  = (const float*)d_in[2];
    const float* amps = (const float*)d_in[3];
    const float* Wmu  = (const float*)d_in[4];
    const float* bmu  = (const float*)d_in[5];
    const float* Wsig = (const float*)d_in[6];
    const float* bsig = (const float*)d_in[7];
    const float* W01  = (const float*)d_in[8];
    const float* b01  = (const float*)d_in[9];
    const float* W1   = (const float*)d_in[10];
    const float* b1   = (const float*)d_in[11];
    const float* W2   = (const float*)d_in[12];
    const float* b2   = (const float*)d_in[13];

    float* out      = (float*)d_out;
    float* filtered = (float*)d_ws;   // B_*NF_ f32 accumulator

    // zero the atomic accumulator every call (harness does not re-poison)
    hipMemsetAsync(filtered, 0, B_ * NF_ * sizeof(float), stream);

    filt_kernel<<<dim3(NG_, B_ / ROWS_), 512, 0, stream>>>(X, mus, amps, filtered);
    head_kernel<<<B_, 256, 0, stream>>>(filtered, eps, Wmu, bmu, Wsig, bsig,
                                        W01, b01, W1, b1, W2, b2, out);
}

// Round 4
// 166.933 us; speedup vs baseline: 1.4578x; 1.2713x over previous
//
#include <hip/hip_runtime.h>
#include <cstdint>
#include <cstddef>

#define B_   128
#define NF_  64
#define L_   4096
#define K_   64
#define NG_  400

#define GP_     8                 // g partitions (grid.x)
#define GITER_  (NG_ / GP_)       // 50 g-tiles per block
#define ROWS_   2                 // batch rows per block
#define PADF_   128               // zero pad each side (window overhang <= 99)
#define ROWPF_  (PADF_ + L_ + PADF_)   // 4352 floats per padded row

constexpr float STEP = 4096.0f / 4095.0f;              // linspace(0,4096,4096) step
constexpr float NEGC = -1.4426950408889634f / 512.0f;  // -log2(e)/(2*sigma^2), sigma=16

// ---------------------------------------------------------------------------
// Persistent filter kernel. Block = (g-partition p, batch-pair b0).
// Double-buffered LDS (2 x 2 rows x 17.4KB = 69.6KB -> 2 blocks/CU, 16 waves).
// Per g-iteration:
//   1. issue next tile's 32KB global loads (4 float4/thread) + mu/amp prefetch
//   2. compute 24 Gaussian window weights for current g (registers)
//   3. windowed dot from LDS: 12x ds_read_b128 + 48 fma/thread
//   4. accumulate acc += sc * dot  (register accumulation across all 50 g)
//   5. vmcnt-drain -> write next tile to LDS[nxt] -> one __syncthreads
// End: 8-lane shfl reduce, ONE partial store per (p,b,f). No atomics/memset.
// ---------------------------------------------------------------------------
__global__ __launch_bounds__(512, 4) void filt_kernel(
    const float* __restrict__ X, const float* __restrict__ mus,
    const float* __restrict__ amps, float* __restrict__ part)
{
    const int p  = blockIdx.x;
    const int b0 = blockIdx.y * ROWS_;
    const int t  = threadIdx.x;
    const int f  = t >> 3;        // filter 0..63
    const int i  = t & 7;         // window float4 slot 0..7

    __shared__ __align__(16) float Xs[2][ROWS_][ROWPF_];

    // zero the pads of both buffers once (front 32 f4, back 32 f4 per row)
    if (t < 256) {
        const int br = t >> 6;            // (buf,row) 0..3
        const int k  = t & 63;
        float4* pr = (float4*)Xs[br >> 1][br & 1];
        const float4 z{0.f, 0.f, 0.f, 0.f};
        if (k < 32) pr[k] = z;
        else        pr[1056 + (k - 32)] = z;   // 4224/4 = 1056
    }

    const float* __restrict__ Xb0 = X + ((size_t)(b0 + 0) * NG_) * L_;
    const float* __restrict__ Xb1 = X + ((size_t)(b0 + 1) * NG_) * L_;

    // ---- prologue: stage tile g0 ----
    int g = p * GITER_;
    float4 xv[4];
    {
        const float4* r0 = (const float4*)(Xb0 + (size_t)g * L_);
        const float4* r1 = (const float4*)(Xb1 + (size_t)g * L_);
        xv[0] = r0[t]; xv[1] = r0[t + 512];
        xv[2] = r1[t]; xv[3] = r1[t + 512];
    }
    float mu_c = mus [f * NG_ + g];
    float sc_c = amps[f * NG_ + g] * (1.0f / 4096.0f);
    {
        float4* d0 = (float4*)(Xs[0][0] + PADF_);
        float4* d1 = (float4*)(Xs[0][1] + PADF_);
        d0[t] = xv[0]; d0[t + 512] = xv[1];
        d1[t] = xv[2]; d1[t + 512] = xv[3];
    }
    __syncthreads();

    float acc0 = 0.f, acc1 = 0.f;
    float mu_n = 0.f, sc_n = 0.f;

    for (int it = 0; it < GITER_; ++it) {
        const int  cur  = it & 1;
        const bool more = (it + 1 < GITER_);
        const int  gn   = g + 1;

        // 1. issue next tile's loads FIRST (latency hides under 2/3)
        if (more) {
            const float4* r0 = (const float4*)(Xb0 + (size_t)gn * L_);
            const float4* r1 = (const float4*)(Xb1 + (size_t)gn * L_);
            xv[0] = r0[t]; xv[1] = r0[t + 512];
            xv[2] = r1[t]; xv[3] = r1[t + 512];
            mu_n = mus [f * NG_ + gn];
            sc_n = amps[f * NG_ + gn] * (1.0f / 4096.0f);
        }

        // 2. Gaussian window weights for current g (no sc — folded at step 4)
        const int   l0 = (((int)mu_c) - 96) & ~3;       // 16B-aligned start
        const float bx = fmaf((float)(l0 + 4 * i), STEP, -mu_c);
        float w[6][4];
#pragma unroll
        for (int c = 0; c < 6; ++c)
#pragma unroll
            for (int j = 0; j < 4; ++j) {
                const float d = bx + (float)(32 * c + j) * STEP;
                w[c][j] = exp2f(NEGC * d * d);
            }

        // 3. windowed dot products from LDS (8 consecutive lanes = 8
        //    consecutive float4 = all 32 banks once -> conflict-free)
        const float* x0 = Xs[cur][0] + PADF_ + l0 + 4 * i;
        const float* x1 = Xs[cur][1] + PADF_ + l0 + 4 * i;
        float d0 = 0.f, d1 = 0.f;
#pragma unroll
        for (int c = 0; c < 6; ++c) {
            const float4 a = *(const float4*)(x0 + 32 * c);
            const float4 b = *(const float4*)(x1 + 32 * c);
            d0 = fmaf(a.x, w[c][0], fmaf(a.y, w[c][1], fmaf(a.z, w[c][2], fmaf(a.w, w[c][3], d0))));
            d1 = fmaf(b.x, w[c][0], fmaf(b.y, w[c][1], fmaf(b.z, w[c][2], fmaf(b.w, w[c][3], d1))));
        }
        // 4. accumulate across g in registers
        acc0 = fmaf(sc_c, d0, acc0);
        acc1 = fmaf(sc_c, d1, acc1);

        // 5. drain + write next tile, single barrier
        if (more) {
            const int nxt = cur ^ 1;
            float4* e0 = (float4*)(Xs[nxt][0] + PADF_);
            float4* e1 = (float4*)(Xs[nxt][1] + PADF_);
            e0[t] = xv[0]; e0[t + 512] = xv[1];
            e1[t] = xv[2]; e1[t + 512] = xv[3];
            mu_c = mu_n; sc_c = sc_n; g = gn;
            __syncthreads();
        }
    }

    // reduce across the 8 lanes sharing this filter (consecutive lanes)
#pragma unroll
    for (int d = 1; d < 8; d <<= 1) {
        acc0 += __shfl_xor(acc0, d);
        acc1 += __shfl_xor(acc1, d);
    }
    if (i == 0) {
        part[((size_t)p * B_ + b0    ) * NF_ + f] = acc0;
        part[((size_t)p * B_ + b0 + 1) * NF_ + f] = acc1;
    }
}

// ---------------------------------------------------------------------------
// MLP head (tiny): sums the 8 g-partition partials, then elu/reparam + 3
// small GEMVs with exact gelu.
// out layout: coms[128*400] | pred[128*400] | mu[128*64] | log_sig[128*64]
// ---------------------------------------------------------------------------
__device__ __forceinline__ float gelu_exact(float x) {
    return 0.5f * x * (1.0f + erff(x * 0.70710678118654752f));
}

__global__ __launch_bounds__(256) void head_kernel(
    const float* __restrict__ part, const float* __restrict__ eps,
    const float* __restrict__ Wmu,  const float* __restrict__ bmu,
    const float* __restrict__ Wsig, const float* __restrict__ bsig,
    const float* __restrict__ W01,  const float* __restrict__ b01,
    const float* __restrict__ W1,   const float* __restrict__ b1,
    const float* __restrict__ W2,   const float* __restrict__ b2,
    float* __restrict__ out)
{
    const int b = blockIdx.x;
    const int t = threadIdx.x;
    __shared__ float fil[NF_], lat[K_], hh[K_];

    if (t < NF_) {
        float s = 0.f;
#pragma unroll
        for (int pp = 0; pp < GP_; ++pp)
            s += part[((size_t)pp * B_ + b) * NF_ + t];
        fil[t] = s;
    }
    __syncthreads();

    if (t < K_) {
        float am = bmu[t], as = bsig[t];
#pragma unroll 8
        for (int fj = 0; fj < NF_; ++fj) {
            float x = fil[fj];
            am = fmaf(x, Wmu [t * NF_ + fj], am);
            as = fmaf(x, Wsig[t * NF_ + fj], as);
        }
        float muv = am > 0.0f ? am : expm1f(am);
        float lsv = as > 0.0f ? as : expm1f(as);
        out[2 * B_ * NG_            + b * K_ + t] = muv;   // mu
        out[2 * B_ * NG_ + B_ * K_  + b * K_ + t] = lsv;   // log_sig
        lat[t] = fmaf(eps[b * K_ + t], expf(lsv), muv);
    }
    __syncthreads();

    if (t < K_) {
        float a = b01[t];
#pragma unroll 8
        for (int j = 0; j < K_; ++j) a = fmaf(lat[j], W01[t * K_ + j], a);
        hh[t] = gelu_exact(a);
    }
    __syncthreads();

    for (int n = t; n < NG_; n += 256) {
        float a1 = b1[n], a2 = b2[n];
#pragma unroll 8
        for (int k = 0; k < K_; ++k) {
            float hk = hh[k];
            a1 = fmaf(hk, W1[n * K_ + k], a1);
            a2 = fmaf(hk, W2[n * K_ + k], a2);
        }
        out[            b * NG_ + n] = gelu_exact(a1);   // coms
        out[B_ * NG_ +  b * NG_ + n] = gelu_exact(a2);   // pred_num_spikes
    }
}

extern "C" void kernel_launch(void* const* d_in, const int* in_sizes, int n_in,
                              void* d_out, int out_size, void* d_ws, size_t ws_size,
                              hipStream_t stream) {
    const float* X    = (const float*)d_in[0];
    const float* eps  = (const float*)d_in[1];
    const float* mus  = (const float*)d_in[2];
    const float* amps = (const float*)d_in[3];
    const float* Wmu  = (const float*)d_in[4];
    const float* bmu  = (const float*)d_in[5];
    const float* Wsig = (const float*)d_in[6];
    const float* bsig = (const float*)d_in[7];
    const float* W01  = (const float*)d_in[8];
    const float* b01  = (const float*)d_in[9];
    const float* W1   = (const float*)d_in[10];
    const float* b1   = (const float*)d_in[11];
    const float* W2   = (const float*)d_in[12];
    const float* b2   = (const float*)d_in[13];

    float* out  = (float*)d_out;
    float* part = (float*)d_ws;   // GP_*B_*NF_ f32 partials (fully overwritten)

    filt_kernel<<<dim3(GP_, B_ / ROWS_), 512, 0, stream>>>(X, mus, amps, part);
    head_kernel<<<B_, 256, 0, stream>>>(part, eps, Wmu, bmu, Wsig, bsig,
                                        W01, b01, W1, b1, W2, b2, out);
}